// Round 11
// baseline (799.066 us; speedup 1.0000x reference)
//
#include <hip/hip_runtime.h>
#include <hip/hip_bf16.h>
#include <hip/hip_fp16.h>

// Renet3d. Matmuls: bf16 MFMA 16x16x32, fp32 accum.
// Scan v11 = v8 handshake + COURIER WAVE: 9-wave blocks; wave 8 polls the partner
// flag (tid0-RMW, v8-proven), pulls the mailbox, scatters to hbuf, raises an LDS
// flag. Compute waves spin on LDS (no global-latency coupling); hbuf parity-dbuf
// removes the mid-step barriers -> 1 __syncthreads per step.
// GEMM: global_load_lds width-16 staging with source-side XOR chunk swizzle.

typedef __attribute__((ext_vector_type(8))) short bf16x8;
typedef __attribute__((ext_vector_type(4))) float f32x4;
typedef __attribute__((ext_vector_type(4))) unsigned int u32x4;
typedef __attribute__((ext_vector_type(2))) unsigned int u32x2;

#define AGENT __HIP_MEMORY_SCOPE_AGENT

__device__ __forceinline__ unsigned short f2bf(float f) {
    unsigned int u = __float_as_uint(f);
    u += 0x7fffu + ((u >> 16) & 1u);
    return (unsigned short)(u >> 16);
}
__device__ __forceinline__ void gload16(const void* g, void* l) {
    __builtin_amdgcn_global_load_lds((const __attribute__((address_space(1))) unsigned int*)g,
                                     (__attribute__((address_space(3))) unsigned int*)l, 16, 0, 0);
}

// ---------------- weight casts ----------------
struct CastW { const float* src[9]; unsigned short* dst[9]; int n[9]; int L[9]; int perm[9]; };
__global__ void k_castw(CastW j) {
    const int a = blockIdx.y;
    const int i = blockIdx.x * 256 + threadIdx.x;
    if (i >= j.n[a]) return;
    const int L = j.L[a];
    const int r = i >> L, c = i & ((1 << L) - 1);
    const int dr = j.perm[a] ? ((r & 255) * 4 + (r >> 8)) : r;
    j.dst[a][(dr << L) | c] = f2bf(j.src[a][i]);
}
struct CastB { const float* src[4]; float* dst[4]; };
__global__ void k_castb(CastB j) {
    const int a = blockIdx.y;
    const int i = blockIdx.x * 256 + threadIdx.x;
    j.dst[a][(i & 255) * 4 + (i >> 8)] = j.src[a][i];
}

// ---------------- gather: 5D f32 -> v_in bf16 [512*16][64] ----------------
__global__ void k_gather(const float* __restrict__ X, unsigned short* __restrict__ vin,
                         int sm, int sa, int sb) {
    const int seq = blockIdx.x;
    const int n = seq >> 4, a = seq & 15;
    const size_t base = (size_t)(n >> 4) * 64 * 4096 + (size_t)sm * (n & 15) + (size_t)sa * a;
    for (int idx = threadIdx.x; idx < 1024; idx += 256) {
        const int c = idx & 63, b = idx >> 6;
        vin[((size_t)seq * 16 + b) * 64 + c] = f2bf(X[base + (size_t)c * 4096 + (size_t)sb * b]);
    }
}

// ---------------- GEMM: z-batched, global_load_lds staging, optional fused 5D scatter ----------------
__global__ __launch_bounds__(256) void k_gemm(const unsigned short* __restrict__ A, int K,
        const unsigned short* __restrict__ W0, const unsigned short* __restrict__ W1,
        const float* __restrict__ bias0, const float* __restrict__ bias1,
        __half* __restrict__ C, int ldc, int nvalid,
        int mode, float* __restrict__ out5d, int sm, int sa, int sb) {
    __shared__ unsigned short Alds[128 * 32];   // linear 64B rows
    __shared__ unsigned short Blds[128 * 32];
    const unsigned short* W = blockIdx.z ? W1 : W0;
    const float* bias = blockIdx.z ? bias1 : bias0;
    C += (size_t)blockIdx.z * 8192 * ldc;
    const int m0 = blockIdx.x * 128, n0 = blockIdx.y * 128;
    const int tid = threadIdx.x;
    const int lane = tid & 63, wid = tid >> 6;
    const int wr = wid >> 1, wc = wid & 1;
    const int fl = lane & 15, fh = lane >> 4;
    f32x4 acc[4][4];
    #pragma unroll
    for (int mi = 0; mi < 4; mi++)
        #pragma unroll
        for (int ni = 0; ni < 4; ni++) { f32x4 z = {0.f,0.f,0.f,0.f}; acc[mi][ni] = z; }

    // staging geometry: per wave 2 calls of 16 rows (64B/row); source chunk XOR-swizzled
    const int srow = wid * 32 + (lane >> 2);
    const int swz = ((lane & 3) ^ ((lane >> 2) & 3)) * 8;   // shorts

    for (int k0 = 0; k0 < K; k0 += 32) {
        __syncthreads();
        gload16(A + (size_t)(m0 + srow) * K + k0 + swz,      &Alds[(wid * 32) * 32]);
        gload16(A + (size_t)(m0 + srow + 16) * K + k0 + swz, &Alds[(wid * 32 + 16) * 32]);
        gload16(W + (size_t)(n0 + srow) * K + k0 + swz,      &Blds[(wid * 32) * 32]);
        gload16(W + (size_t)(n0 + srow + 16) * K + k0 + swz, &Blds[(wid * 32 + 16) * 32]);
        __syncthreads();
        bf16x8 af[4], bfb[4];
        const int rc = (fh ^ (fl & 3)) * 8;   // swizzled chunk (row&3 == fl&3 for our rows)
        #pragma unroll
        for (int i = 0; i < 4; i++) {
            af[i]  = *(const bf16x8*)&Alds[(wr * 64 + i * 16 + fl) * 32 + rc];
            bfb[i] = *(const bf16x8*)&Blds[(wc * 64 + i * 16 + fl) * 32 + rc];
        }
        #pragma unroll
        for (int mi = 0; mi < 4; mi++)
            #pragma unroll
            for (int ni = 0; ni < 4; ni++)
                acc[mi][ni] = __builtin_amdgcn_mfma_f32_16x16x32_bf16(af[mi], bfb[ni], acc[mi][ni], 0, 0, 0);
    }
    const int rl = fh * 4;
    #pragma unroll
    for (int ni = 0; ni < 4; ni++) {
        const int col = n0 + wc * 64 + ni * 16 + fl;
        if (col < nvalid) {
            const float bs = bias[col];
            #pragma unroll
            for (int mi = 0; mi < 4; mi++) {
                const int row = m0 + wr * 64 + mi * 16 + rl;
                #pragma unroll
                for (int j = 0; j < 4; j++) {
                    const float v = acc[mi][ni][j] + bs;
                    if (mode) {
                        const int r = row + j;
                        const int n_ = r >> 8, b_ = (r >> 4) & 15, a_ = r & 15;
                        out5d[(size_t)(n_ >> 4) * 262144 + (size_t)sm * (n_ & 15) +
                              (size_t)sa * a_ + (size_t)sb * b_ + (size_t)col * 4096] = v;
                    } else {
                        C[(size_t)(row + j) * ldc + col] = __float2half(v);
                    }
                }
            }
        }
    }
}

// ---------------- LSTM scan v11: courier wave ----------------
// grid (32, 2, 2): st, dir, kh. 576 threads = 8 compute waves + 1 courier wave.
// hbuf parity-double-buffered; one __syncthreads (F) per step. Courier: poll -> pull
// -> scatter to hbuf -> LDS flag. Publish path identical to v8.
__global__ __launch_bounds__(576, 1) void k_scan(const __half* __restrict__ xw,
        const unsigned short* __restrict__ whh_f, const unsigned short* __restrict__ whh_b,
        unsigned short* __restrict__ out, int out_mode,
        unsigned long long* __restrict__ HX, unsigned int* __restrict__ FLG, int phase) {
    __shared__ __align__(16) char gbuf[512 * 40];     // gates f16 [512 cols][20 s-slots]
    __shared__ __align__(16) char hbuf[2 * 8192];     // h bf16 dbuf [16 s][256 k], XOR-swizzled
    __shared__ int sflag[16];
    const int tid = threadIdx.x;
    const int lane = tid & 63, w = tid >> 6;          // w==8 -> courier
    const int fl = lane & 15, fh = lane >> 4;
    const int st = blockIdx.x, dir = blockIdx.y, kh = blockIdx.z;
    const int seq0 = st * 16;
    const unsigned short* whh_k = (dir ? whh_b : whh_f) + (size_t)kh * 512 * 256;
    const __half* xwd = xw + (size_t)dir * (8192 * 1024);
    const int slot = ((dir * 32 + st) * 2 + kh);
    unsigned long long* hx_me = HX + (size_t)slot * 1024;
    const unsigned long long* hx_p = HX + (size_t)(slot ^ 1) * 1024;
    unsigned int* flg_me = FLG + slot * 64;
    unsigned int* flg_p  = FLG + (slot ^ 1) * 64;
    const unsigned int base = 16u * (unsigned int)phase;
    const int kOwnB = kh * 4;          // address-only
    const int kParB = (1 - kh) * 4;    // address-only

    if (tid < 16) sflag[tid] = 0;
    for (int i = tid; i < 2048; i += 576) ((unsigned int*)(hbuf + 8192))[i] = 0u;  // h(-1)=0

    bf16x8 wown[4][4], wpar[4][4];
    unsigned int xh[4][2], xhn[4][2];
    const int C0g = kh * 512 + w * 64;
    int tt = dir ? 15 : 0;
    const int tstep = dir ? -1 : 1;
    if (w < 8) {
        #pragma unroll
        for (int nt = 0; nt < 4; nt++) {
            const unsigned short* rowp = whh_k + (size_t)(w * 64 + nt * 16 + fl) * 256 + fh * 8;
            #pragma unroll
            for (int i = 0; i < 4; i++) {
                wown[nt][i] = *(const bf16x8*)(rowp + (kOwnB + i) * 32);
                wpar[nt][i] = *(const bf16x8*)(rowp + (kParB + i) * 32);
            }
        }
        #pragma unroll
        for (int nt = 0; nt < 4; nt++)
            #pragma unroll
            for (int j2 = 0; j2 < 2; j2++) {
                const size_t b_ = ((size_t)(seq0 + fh * 4 + j2 * 2) * 16 + tt) * 1024 + C0g + nt * 16 + fl;
                const unsigned short h0 = __half_as_ushort(xwd[b_]);
                const unsigned short h1 = __half_as_ushort(xwd[b_ + 16 * 1024]);
                xh[nt][j2] = (unsigned int)h0 | ((unsigned int)h1 << 16);
            }
    }
    __syncthreads();

    if (w == 8) {
        // ---------------- courier wave ----------------
        for (int t = 0; t < 16; t++) {
            if (t > 0) {
                if (lane == 0) {
                    const unsigned int want = base + (unsigned int)t;
                    while (atomicAdd(flg_p, 0u) < want) __builtin_amdgcn_s_sleep(1);
                }
                const unsigned long long* src = hx_p + ((t - 1) & 1) * 512;
                unsigned long long pv[8];
                #pragma unroll
                for (int e = 0; e < 8; e++)
                    pv[e] = __hip_atomic_load(src + lane + e * 64, __ATOMIC_RELAXED, AGENT);
                char* hwbuf = hbuf + ((t - 1) & 1) * 8192;
                #pragma unroll
                for (int e = 0; e < 8; e++) {
                    const int idx = lane + e * 64;
                    const int kl = idx >> 2, sl0 = (idx & 3) * 4;
                    const int kp = (1 - kh) * 128 + kl;
                    #pragma unroll
                    for (int e2 = 0; e2 < 4; e2++) {
                        const int s = sl0 + e2;
                        *(unsigned short*)(hwbuf + ((s * 512 + kp * 2) ^ ((s & 7) << 4))) =
                            (unsigned short)(pv[e] >> (16 * e2));
                    }
                }
                asm volatile("s_waitcnt lgkmcnt(0)" ::: "memory");
                if (lane == 0) *(volatile int*)&sflag[t] = 1;
            }
            __syncthreads();   // F (matches compute)
        }
        return;
    }

    // ---------------- compute waves ----------------
    const int li = lane & 15, ls = lane >> 4;
    const int khalf = w * 16 + li;
    const int kglob = kh * 128 + khalf;
    float c_reg[4] = {0.f, 0.f, 0.f, 0.f};

    for (int t = 0; t < 16; t++) {
        const char* hread = hbuf + ((t - 1) & 1) * 8192;
        char* hwr = hbuf + (t & 1) * 8192;
        // ---- copy-out h(t-1) own half ----
        if (t > 0) {
            const int ttp = tt - tstep;
            const int s = tid >> 5, q = tid & 31;
            const int ba = (s * 512 + (kh * 128 + q * 4) * 2) ^ ((s & 7) << 4);
            const u32x2 hv = *(const u32x2*)(hread + ba);
            const size_t row = out_mode ? ((size_t)(seq0 + s) * 16 + ttp)
                                        : ((size_t)st * 256 + (size_t)ttp * 16 + s);
            *(u32x2*)(out + row * 512 + dir * 256 + kh * 128 + q * 4) = hv;
        }
        // ---- own-half A-frags + own-half MFMAs ----
        bf16x8 afr[4];
        #pragma unroll
        for (int i = 0; i < 4; i++) {
            const int ba = (fl * 512 + (kOwnB + i) * 64 + fh * 16) ^ ((fl & 7) << 4);
            afr[i] = *(const bf16x8*)(hread + ba);
        }
        f32x4 acc[4];
        #pragma unroll
        for (int nt = 0; nt < 4; nt++) {
            acc[nt][0] = __half2float(__ushort_as_half((unsigned short)(xh[nt][0] & 0xffff)));
            acc[nt][1] = __half2float(__ushort_as_half((unsigned short)(xh[nt][0] >> 16)));
            acc[nt][2] = __half2float(__ushort_as_half((unsigned short)(xh[nt][1] & 0xffff)));
            acc[nt][3] = __half2float(__ushort_as_half((unsigned short)(xh[nt][1] >> 16)));
            #pragma unroll
            for (int i = 0; i < 4; i++)
                acc[nt] = __builtin_amdgcn_mfma_f32_16x16x32_bf16(afr[i], wown[nt][i], acc[nt], 0, 0, 0);
        }
        // ---- xw prefetch for t+1 (latency hidden under spin + partner phase) ----
        const int tn = (t < 15) ? tt + tstep : tt;
        #pragma unroll
        for (int nt = 0; nt < 4; nt++)
            #pragma unroll
            for (int j2 = 0; j2 < 2; j2++) {
                const size_t b_ = ((size_t)(seq0 + fh * 4 + j2 * 2) * 16 + tn) * 1024 + C0g + nt * 16 + fl;
                const unsigned short h0 = __half_as_ushort(xwd[b_]);
                const unsigned short h1 = __half_as_ushort(xwd[b_ + 16 * 1024]);
                xhn[nt][j2] = (unsigned int)h0 | ((unsigned int)h1 << 16);
            }
        // ---- spin on courier's LDS flag (partner half ready in hread) ----
        if (t > 0) {
            volatile int* sf = (volatile int*)&sflag[t];
            while (*sf == 0) { }
            asm volatile("" ::: "memory");
        }
        // ---- partner-half MFMAs ----
        #pragma unroll
        for (int i = 0; i < 4; i++) {
            const int ba = (fl * 512 + (kParB + i) * 64 + fh * 16) ^ ((fl & 7) << 4);
            afr[i] = *(const bf16x8*)(hread + ba);
        }
        #pragma unroll
        for (int nt = 0; nt < 4; nt++) {
            #pragma unroll
            for (int i = 0; i < 4; i++)
                acc[nt] = __builtin_amdgcn_mfma_f32_16x16x32_bf16(afr[i], wpar[nt][i], acc[nt], 0, 0, 0);
            const int coll = w * 64 + nt * 16 + fl;
            const unsigned int lo = (unsigned int)__half_as_ushort(__float2half(acc[nt][0])) |
                                    ((unsigned int)__half_as_ushort(__float2half(acc[nt][1])) << 16);
            const unsigned int hi = (unsigned int)__half_as_ushort(__float2half(acc[nt][2])) |
                                    ((unsigned int)__half_as_ushort(__float2half(acc[nt][3])) << 16);
            u32x2 pk = {lo, hi};
            *(u32x2*)(gbuf + coll * 40 + fh * 8) = pk;
        }
        // ---- nonlinearity (wave-local gbuf cols; writes h(t) into hwr own cells) ----
        float gv[4][4];
        const int colbase = w * 64 + 4 * li;
        #pragma unroll
        for (int g = 0; g < 4; g++) {
            const u32x2 a = *(const u32x2*)(gbuf + (colbase + g) * 40 + ls * 8);
            gv[g][0] = __half2float(__ushort_as_half((unsigned short)(a[0] & 0xffff)));
            gv[g][1] = __half2float(__ushort_as_half((unsigned short)(a[0] >> 16)));
            gv[g][2] = __half2float(__ushort_as_half((unsigned short)(a[1] & 0xffff)));
            gv[g][3] = __half2float(__ushort_as_half((unsigned short)(a[1] >> 16)));
        }
        unsigned long long hpack = 0ull;
        #pragma unroll
        for (int p2 = 0; p2 < 4; p2++) {
            const float ig = 1.f / (1.f + __expf(-gv[0][p2]));
            const float fg = 1.f / (1.f + __expf(-gv[1][p2]));
            const float e2 = __expf(2.f * gv[2][p2]);
            const float gg = 1.f - 2.f / (e2 + 1.f);
            const float og = 1.f / (1.f + __expf(-gv[3][p2]));
            const float c = fg * c_reg[p2] + ig * gg;
            c_reg[p2] = c;
            const float e2c = __expf(2.f * c);
            const float hv = og * (1.f - 2.f / (e2c + 1.f));
            const unsigned short hb = f2bf(hv);
            const int s = ls * 4 + p2;
            *(unsigned short*)(hwr + ((s * 512 + kglob * 2) ^ ((s & 7) << 4))) = hb;
            hpack |= ((unsigned long long)hb) << (16 * p2);
        }
        // ---- publish (relaxed; F drains) ----
        if (t < 15)
            __hip_atomic_store(hx_me + ((t & 1) * 512 + khalf * 4 + ls), hpack, __ATOMIC_RELAXED, AGENT);
        #pragma unroll
        for (int nt = 0; nt < 4; nt++) { xh[nt][0] = xhn[nt][0]; xh[nt][1] = xhn[nt][1]; }
        tt = tn;
        __syncthreads();   // F
        if (t < 15 && tid == 0)
            atomicExch(flg_me, base + (unsigned int)(t + 1));
    }
    // epilogue: copy-out h(15) own half (in hbuf[15&1] = hbuf+8192)
    {
        const int s = tid >> 5, q = tid & 31;
        const int ba = (s * 512 + (kh * 128 + q * 4) * 2) ^ ((s & 7) << 4);
        const u32x2 hv = *(const u32x2*)(hbuf + 8192 + ba);
        const size_t row = out_mode ? ((size_t)(seq0 + s) * 16 + tt)
                                    : ((size_t)st * 256 + (size_t)tt * 16 + s);
        *(u32x2*)(out + row * 512 + dir * 256 + kh * 128 + q * 4) = hv;
    }
}

// ---------------- final conv3d 1x1x1: reads CONV f16 directly via index map ----------------
__global__ __launch_bounds__(256) void k_conv3f(const __half* __restrict__ CONV,
        const float* __restrict__ w, const float* __restrict__ bias, float* __restrict__ out) {
    __shared__ float xl[64 * 32];
    __shared__ float wl[64 * 64];
    const int bb = blockIdx.y;
    const int p0 = blockIdx.x * 32;
    const int tid = threadIdx.x;
    for (int i = tid; i < 64 * 32; i += 256) {
        const int c = i & 63, pp = i >> 6;
        const int p = p0 + pp;
        const int n_ = bb * 16 + (p & 15), b_ = (p >> 4) & 15, a_ = (p >> 8) & 15;
        const int r = (n_ * 16 + b_) * 16 + a_;
        xl[c * 32 + pp] = __half2float(CONV[(size_t)r * 64 + c]);
    }
    for (int i = tid; i < 64 * 64; i += 256) wl[i] = w[i];
    __syncthreads();
    const int pp = tid & 31, og = tid >> 5;
    #pragma unroll
    for (int oj = 0; oj < 8; oj++) {
        const int o = og * 8 + oj;
        float acc = bias[o];
        #pragma unroll 16
        for (int c = 0; c < 64; c++) acc += xl[c * 32 + pp] * wl[o * 64 + c];
        out[((size_t)bb * 64 + o) * 4096 + p0 + pp] = acc;
    }
}

extern "C" void kernel_launch(void* const* d_in, const int* in_sizes, int n_in,
                              void* d_out, int out_size, void* d_ws, size_t ws_size,
                              hipStream_t stream) {
    (void)in_sizes; (void)n_in; (void)out_size; (void)ws_size;
    const float* x     = (const float*)d_in[0];
    const float* vwihf = (const float*)d_in[1];
    const float* vwhhf = (const float*)d_in[2];
    const float* vbf   = (const float*)d_in[3];
    const float* vwihb = (const float*)d_in[4];
    const float* vwhhb = (const float*)d_in[5];
    const float* vbb   = (const float*)d_in[6];
    const float* hwihf = (const float*)d_in[7];
    const float* hwhhf = (const float*)d_in[8];
    const float* hbf   = (const float*)d_in[9];
    const float* hwihb = (const float*)d_in[10];
    const float* hwhhb = (const float*)d_in[11];
    const float* hbb   = (const float*)d_in[12];
    const float* c2w   = (const float*)d_in[13];
    const float* c2b   = (const float*)d_in[14];
    const float* c3w   = (const float*)d_in[15];
    const float* c3b   = (const float*)d_in[16];

    char* p = (char*)d_ws;
    auto alloc = [&](size_t bytes) { char* r = p; p += (bytes + 255) & ~((size_t)255); return r; };
    unsigned short* bVWIHf = (unsigned short*)alloc((size_t)1024 * 64 * 2);
    unsigned short* bVWIHb = (unsigned short*)alloc((size_t)1024 * 64 * 2);
    unsigned short* bVWHHf = (unsigned short*)alloc((size_t)1024 * 256 * 2);
    unsigned short* bVWHHb = (unsigned short*)alloc((size_t)1024 * 256 * 2);
    unsigned short* bHWIHf = (unsigned short*)alloc((size_t)1024 * 512 * 2);
    unsigned short* bHWIHb = (unsigned short*)alloc((size_t)1024 * 512 * 2);
    unsigned short* bHWHHf = (unsigned short*)alloc((size_t)1024 * 256 * 2);
    unsigned short* bHWHHb = (unsigned short*)alloc((size_t)1024 * 256 * 2);
    unsigned short* bC2W   = (unsigned short*)alloc((size_t)128 * 512 * 2);
    float* pVBf = (float*)alloc(1024 * 4);
    float* pVBb = (float*)alloc(1024 * 4);
    float* pHBf = (float*)alloc(1024 * 4);
    float* pHBb = (float*)alloc(1024 * 4);
    unsigned long long* HX = (unsigned long long*)alloc((size_t)128 * 8192);
    unsigned int* FLG = (unsigned int*)alloc((size_t)128 * 256);
    float* XA = (float*)alloc((size_t)524288 * 4);
    float* XB = (float*)alloc((size_t)524288 * 4);
    unsigned short* VIN = (unsigned short*)alloc((size_t)8192 * 64 * 2);
    __half* XW = (__half*)alloc((size_t)2 * 8192 * 1024 * 2);
    unsigned short* S_   = (unsigned short*)alloc((size_t)8192 * 512 * 2);
    unsigned short* HOUT = (unsigned short*)alloc((size_t)8192 * 512 * 2);
    __half* CONV = (__half*)VIN;   // reuse (VIN dead by conv time)

    hipMemsetAsync(bC2W, 0, (size_t)128 * 512 * 2, stream);
    hipMemsetAsync(FLG, 0, (size_t)128 * 256, stream);
    CastW cw;
    const float* srcs[9] = {vwihf, vwihb, vwhhf, vwhhb, hwihf, hwihb, hwhhf, hwhhb, c2w};
    unsigned short* dsts[9] = {bVWIHf, bVWIHb, bVWHHf, bVWHHb, bHWIHf, bHWIHb, bHWHHf, bHWHHb, bC2W};
    const int ns[9] = {65536, 65536, 262144, 262144, 524288, 524288, 262144, 262144, 32768};
    const int Ls[9] = {6, 6, 8, 8, 9, 9, 8, 8, 9};
    const int pm[9] = {1, 1, 1, 1, 1, 1, 1, 1, 0};
    for (int i = 0; i < 9; i++) { cw.src[i] = srcs[i]; cw.dst[i] = dsts[i]; cw.n[i] = ns[i]; cw.L[i] = Ls[i]; cw.perm[i] = pm[i]; }
    k_castw<<<dim3(2048, 9), 256, 0, stream>>>(cw);
    CastB cb;
    cb.src[0] = vbf; cb.dst[0] = pVBf;
    cb.src[1] = vbb; cb.dst[1] = pVBb;
    cb.src[2] = hbf; cb.dst[2] = pHBf;
    cb.src[3] = hbb; cb.dst[3] = pHBb;
    k_castb<<<dim3(4, 4), 256, 0, stream>>>(cb);

    const int SMs[3] = {256, 16, 1}, SAs[3] = {16, 256, 256}, SBs[3] = {1, 1, 16};
    for (int s = 0; s < 3; s++) {
        const float* Xin = (s == 0) ? x : ((s == 1) ? XA : XB);
        float* Xout = (s == 0) ? XA : XB;
        k_gather<<<512, 256, 0, stream>>>(Xin, VIN, SMs[s], SAs[s], SBs[s]);
        k_gemm<<<dim3(64, 8, 2), 256, 0, stream>>>(VIN, 64, bVWIHf, bVWIHb, pVBf, pVBb,
                                                   XW, 1024, 1024, 0, nullptr, 0, 0, 0);
        k_scan<<<dim3(32, 2, 2), 576, 0, stream>>>(XW, bVWHHf, bVWHHb, S_, 0, HX, FLG, s * 2 + 0);
        k_gemm<<<dim3(64, 8, 2), 256, 0, stream>>>(S_, 512, bHWIHf, bHWIHb, pHBf, pHBb,
                                                   XW, 1024, 1024, 0, nullptr, 0, 0, 0);
        k_scan<<<dim3(32, 2, 2), 576, 0, stream>>>(XW, bHWHHf, bHWHHb, HOUT, 1, HX, FLG, s * 2 + 1);
        if (s < 2)
            k_gemm<<<dim3(64, 1, 1), 256, 0, stream>>>(HOUT, 512, bC2W, bC2W, c2b, c2b,
                                                       CONV, 64, 64, 1, Xout, SMs[s], SAs[s], SBs[s]);
        else
            k_gemm<<<dim3(64, 1, 1), 256, 0, stream>>>(HOUT, 512, bC2W, bC2W, c2b, c2b,
                                                       CONV, 64, 64, 0, nullptr, 0, 0, 0);
    }
    k_conv3f<<<dim3(128, 2), 256, 0, stream>>>(CONV, c3w, c3b, (float*)d_out);
}

// Round 12
// 585.638 us; speedup vs baseline: 1.3644x; 1.3644x over previous
//
#include <hip/hip_runtime.h>
#include <hip/hip_bf16.h>
#include <hip/hip_fp16.h>

// Renet3d. Matmuls: bf16 MFMA 16x16x32, fp32 accum.
// v12 = v10 scan (proven 59.9us: tid0-RMW poll, padded flag, parallel relaxed pull,
// parity-dbuf mailbox, raw E1/E2 barriers, flag after F) + v11 GEMM (global_load_lds
// width-16, source-side XOR chunk swizzle) + coalesced gather (b-inner reads, LDS
// transpose, u64 writes). Conv scatter fused in GEMM epilogue; conv3 reads CONV direct.

typedef __attribute__((ext_vector_type(8))) short bf16x8;
typedef __attribute__((ext_vector_type(4))) float f32x4;
typedef __attribute__((ext_vector_type(4))) unsigned int u32x4;
typedef __attribute__((ext_vector_type(2))) unsigned int u32x2;

#define AGENT __HIP_MEMORY_SCOPE_AGENT

__device__ __forceinline__ unsigned short f2bf(float f) {
    unsigned int u = __float_as_uint(f);
    u += 0x7fffu + ((u >> 16) & 1u);
    return (unsigned short)(u >> 16);
}
__device__ __forceinline__ void gload16(const void* g, void* l) {
    __builtin_amdgcn_global_load_lds((const __attribute__((address_space(1))) unsigned int*)g,
                                     (__attribute__((address_space(3))) unsigned int*)l, 16, 0, 0);
}

// ---------------- weight casts ----------------
struct CastW { const float* src[9]; unsigned short* dst[9]; int n[9]; int L[9]; int perm[9]; };
__global__ void k_castw(CastW j) {
    const int a = blockIdx.y;
    const int i = blockIdx.x * 256 + threadIdx.x;
    if (i >= j.n[a]) return;
    const int L = j.L[a];
    const int r = i >> L, c = i & ((1 << L) - 1);
    const int dr = j.perm[a] ? ((r & 255) * 4 + (r >> 8)) : r;
    j.dst[a][(dr << L) | c] = f2bf(j.src[a][i]);
}
struct CastB { const float* src[4]; float* dst[4]; };
__global__ void k_castb(CastB j) {
    const int a = blockIdx.y;
    const int i = blockIdx.x * 256 + threadIdx.x;
    j.dst[a][(i & 255) * 4 + (i >> 8)] = j.src[a][i];
}

// ---------------- gather: 5D f32 -> v_in bf16 [512*16][64], coalesced reads ----------------
// elem (b,c): X[base + c*4096 + sb*b] -> vin[seq*1024 + b*64 + c]
__global__ void k_gather(const float* __restrict__ X, unsigned short* __restrict__ vin,
                         int sm, int sa, int sb) {
    __shared__ unsigned short sd[16 * 68];
    const int seq = blockIdx.x;
    const int n = seq >> 4, a = seq & 15;
    const size_t base = (size_t)(n >> 4) * 64 * 4096 + (size_t)sm * (n & 15) + (size_t)sa * a;
    const int t = threadIdx.x;
    #pragma unroll
    for (int j = 0; j < 4; j++) {
        const int i = t + j * 256;            // b inner -> 16 lanes read contiguous (sb=1)
        const int c = i >> 4, b = i & 15;
        sd[b * 68 + c] = f2bf(X[base + (size_t)c * 4096 + (size_t)sb * b]);
    }
    __syncthreads();
    const int r = t >> 4, c0 = (t & 15) * 4;
    unsigned long long v;
    unsigned short* sp = &sd[r * 68 + c0];
    v = (unsigned long long)sp[0] | ((unsigned long long)sp[1] << 16) |
        ((unsigned long long)sp[2] << 32) | ((unsigned long long)sp[3] << 48);
    *(unsigned long long*)(vin + (size_t)seq * 1024 + r * 64 + c0) = v;
}

// ---------------- GEMM: z-batched, global_load_lds staging, optional fused 5D scatter ----------------
__global__ __launch_bounds__(256) void k_gemm(const unsigned short* __restrict__ A, int K,
        const unsigned short* __restrict__ W0, const unsigned short* __restrict__ W1,
        const float* __restrict__ bias0, const float* __restrict__ bias1,
        __half* __restrict__ C, int ldc, int nvalid,
        int mode, float* __restrict__ out5d, int sm, int sa, int sb) {
    __shared__ unsigned short Alds[128 * 32];   // linear 64B rows
    __shared__ unsigned short Blds[128 * 32];
    const unsigned short* W = blockIdx.z ? W1 : W0;
    const float* bias = blockIdx.z ? bias1 : bias0;
    C += (size_t)blockIdx.z * 8192 * ldc;
    const int m0 = blockIdx.x * 128, n0 = blockIdx.y * 128;
    const int tid = threadIdx.x;
    const int lane = tid & 63, wid = tid >> 6;
    const int wr = wid >> 1, wc = wid & 1;
    const int fl = lane & 15, fh = lane >> 4;
    f32x4 acc[4][4];
    #pragma unroll
    for (int mi = 0; mi < 4; mi++)
        #pragma unroll
        for (int ni = 0; ni < 4; ni++) { f32x4 z = {0.f,0.f,0.f,0.f}; acc[mi][ni] = z; }

    const int srow = wid * 32 + (lane >> 2);
    const int swz = ((lane & 3) ^ ((lane >> 2) & 3)) * 8;   // shorts

    for (int k0 = 0; k0 < K; k0 += 32) {
        __syncthreads();
        gload16(A + (size_t)(m0 + srow) * K + k0 + swz,      &Alds[(wid * 32) * 32]);
        gload16(A + (size_t)(m0 + srow + 16) * K + k0 + swz, &Alds[(wid * 32 + 16) * 32]);
        gload16(W + (size_t)(n0 + srow) * K + k0 + swz,      &Blds[(wid * 32) * 32]);
        gload16(W + (size_t)(n0 + srow + 16) * K + k0 + swz, &Blds[(wid * 32 + 16) * 32]);
        __syncthreads();
        bf16x8 af[4], bfb[4];
        const int rc = (fh ^ (fl & 3)) * 8;
        #pragma unroll
        for (int i = 0; i < 4; i++) {
            af[i]  = *(const bf16x8*)&Alds[(wr * 64 + i * 16 + fl) * 32 + rc];
            bfb[i] = *(const bf16x8*)&Blds[(wc * 64 + i * 16 + fl) * 32 + rc];
        }
        #pragma unroll
        for (int mi = 0; mi < 4; mi++)
            #pragma unroll
            for (int ni = 0; ni < 4; ni++)
                acc[mi][ni] = __builtin_amdgcn_mfma_f32_16x16x32_bf16(af[mi], bfb[ni], acc[mi][ni], 0, 0, 0);
    }
    const int rl = fh * 4;
    #pragma unroll
    for (int ni = 0; ni < 4; ni++) {
        const int col = n0 + wc * 64 + ni * 16 + fl;
        if (col < nvalid) {
            const float bs = bias[col];
            #pragma unroll
            for (int mi = 0; mi < 4; mi++) {
                const int row = m0 + wr * 64 + mi * 16 + rl;
                #pragma unroll
                for (int j = 0; j < 4; j++) {
                    const float v = acc[mi][ni][j] + bs;
                    if (mode) {
                        const int r = row + j;
                        const int n_ = r >> 8, b_ = (r >> 4) & 15, a_ = r & 15;
                        out5d[(size_t)(n_ >> 4) * 262144 + (size_t)sm * (n_ & 15) +
                              (size_t)sa * a_ + (size_t)sb * b_ + (size_t)col * 4096] = v;
                    } else {
                        C[(size_t)(row + j) * ldc + col] = __float2half(v);
                    }
                }
            }
        }
    }
}

// ---------------- LSTM scan (v10, proven) ----------------
__global__ __launch_bounds__(512, 2) void k_scan(const __half* __restrict__ xw,
        const unsigned short* __restrict__ whh_f, const unsigned short* __restrict__ whh_b,
        unsigned short* __restrict__ out, int out_mode,
        unsigned long long* __restrict__ HX, unsigned int* __restrict__ FLG, int phase) {
    __shared__ __align__(16) char gbuf[512 * 40];
    __shared__ __align__(16) char hbuf[16 * 512];
    const int tid = threadIdx.x;
    const int lane = tid & 63, w = tid >> 6;
    const int fl = lane & 15, fh = lane >> 4;
    const int st = blockIdx.x, dir = blockIdx.y, kh = blockIdx.z;
    const int seq0 = st * 16;
    const unsigned short* whh_k = (dir ? whh_b : whh_f) + (size_t)kh * 512 * 256;
    const __half* xwd = xw + (size_t)dir * (8192 * 1024);
    const int C0g = kh * 512 + w * 64;
    const int slot = ((dir * 32 + st) * 2 + kh);
    unsigned long long* hx_me = HX + (size_t)slot * 1024;
    const unsigned long long* hx_p = HX + (size_t)(slot ^ 1) * 1024;
    unsigned int* flg_me = FLG + slot * 64;
    unsigned int* flg_p  = FLG + (slot ^ 1) * 64;
    const unsigned int base = 16u * (unsigned int)phase;
    const int kOwnB = kh * 4;
    const int kParB = (1 - kh) * 4;

    #pragma unroll
    for (int i = 0; i < 4; i++) ((unsigned int*)hbuf)[tid + i * 512] = 0u;

    bf16x8 wown[4][4], wpar[4][4];
    #pragma unroll
    for (int nt = 0; nt < 4; nt++) {
        const unsigned short* rowp = whh_k + (size_t)(w * 64 + nt * 16 + fl) * 256 + fh * 8;
        #pragma unroll
        for (int i = 0; i < 4; i++) {
            wown[nt][i] = *(const bf16x8*)(rowp + (kOwnB + i) * 32);
            wpar[nt][i] = *(const bf16x8*)(rowp + (kParB + i) * 32);
        }
    }

    const int li = lane & 15, ls = lane >> 4;
    const int khalf = w * 16 + li;
    const int kglob = kh * 128 + khalf;
    float c_reg[4] = {0.f, 0.f, 0.f, 0.f};

    int tt = dir ? 15 : 0;
    const int tstep = dir ? -1 : 1;

    unsigned int xh[4][2], xhn[4][2];
    #pragma unroll
    for (int nt = 0; nt < 4; nt++)
        #pragma unroll
        for (int j2 = 0; j2 < 2; j2++) {
            const size_t b_ = ((size_t)(seq0 + fh * 4 + j2 * 2) * 16 + tt) * 1024 + C0g + nt * 16 + fl;
            const unsigned short h0 = __half_as_ushort(xwd[b_]);
            const unsigned short h1 = __half_as_ushort(xwd[b_ + 16 * 1024]);
            xh[nt][j2] = (unsigned int)h0 | ((unsigned int)h1 << 16);
        }

    __syncthreads();

    for (int t = 0; t < 16; t++) {
        if (t > 0) {
            const int ttp = tt - tstep;
            const int s = tid >> 5, q = tid & 31;
            const int ba = (s * 512 + (kh * 128 + q * 4) * 2) ^ ((s & 7) << 4);
            const u32x2 hv = *(const u32x2*)(hbuf + ba);
            const size_t row = out_mode ? ((size_t)(seq0 + s) * 16 + ttp)
                                        : ((size_t)st * 256 + (size_t)ttp * 16 + s);
            *(u32x2*)(out + row * 512 + dir * 256 + kh * 128 + q * 4) = hv;
        }
        bf16x8 afr[4];
        #pragma unroll
        for (int i = 0; i < 4; i++) {
            const int ba = (fl * 512 + (kOwnB + i) * 64 + fh * 16) ^ ((fl & 7) << 4);
            afr[i] = *(const bf16x8*)(hbuf + ba);
        }
        f32x4 acc[4];
        #pragma unroll
        for (int nt = 0; nt < 4; nt++) {
            acc[nt][0] = __half2float(__ushort_as_half((unsigned short)(xh[nt][0] & 0xffff)));
            acc[nt][1] = __half2float(__ushort_as_half((unsigned short)(xh[nt][0] >> 16)));
            acc[nt][2] = __half2float(__ushort_as_half((unsigned short)(xh[nt][1] & 0xffff)));
            acc[nt][3] = __half2float(__ushort_as_half((unsigned short)(xh[nt][1] >> 16)));
            #pragma unroll
            for (int i = 0; i < 4; i++)
                acc[nt] = __builtin_amdgcn_mfma_f32_16x16x32_bf16(afr[i], wown[nt][i], acc[nt], 0, 0, 0);
        }
        if (t > 0) {
            if (tid == 0) {
                const unsigned int want = base + (unsigned int)t;
                while (atomicAdd(flg_p, 0u) < want) __builtin_amdgcn_s_sleep(1);
            }
            asm volatile("s_barrier" ::: "memory");   // E1: control-only
            const unsigned long long pv =
                __hip_atomic_load(hx_p + (((t - 1) & 1) * 512 + tid), __ATOMIC_RELAXED, AGENT);
            const int kl = tid >> 2, sl0 = (tid & 3) * 4;
            const int kp = (1 - kh) * 128 + kl;
            #pragma unroll
            for (int e = 0; e < 4; e++) {
                const int s = sl0 + e;
                *(unsigned short*)(hbuf + ((s * 512 + kp * 2) ^ ((s & 7) << 4))) =
                    (unsigned short)(pv >> (16 * e));
            }
        }
        asm volatile("s_waitcnt lgkmcnt(0)\n\ts_barrier" ::: "memory");   // E2: LDS-only

        const int tn = (t < 15) ? tt + tstep : tt;
        #pragma unroll
        for (int nt = 0; nt < 4; nt++)
            #pragma unroll
            for (int j2 = 0; j2 < 2; j2++) {
                const size_t b_ = ((size_t)(seq0 + fh * 4 + j2 * 2) * 16 + tn) * 1024 + C0g + nt * 16 + fl;
                const unsigned short h0 = __half_as_ushort(xwd[b_]);
                const unsigned short h1 = __half_as_ushort(xwd[b_ + 16 * 1024]);
                xhn[nt][j2] = (unsigned int)h0 | ((unsigned int)h1 << 16);
            }

        #pragma unroll
        for (int i = 0; i < 4; i++) {
            const int ba = (fl * 512 + (kParB + i) * 64 + fh * 16) ^ ((fl & 7) << 4);
            afr[i] = *(const bf16x8*)(hbuf + ba);
        }
        #pragma unroll
        for (int nt = 0; nt < 4; nt++) {
            #pragma unroll
            for (int i = 0; i < 4; i++)
                acc[nt] = __builtin_amdgcn_mfma_f32_16x16x32_bf16(afr[i], wpar[nt][i], acc[nt], 0, 0, 0);
            const int coll = w * 64 + nt * 16 + fl;
            const unsigned int lo = (unsigned int)__half_as_ushort(__float2half(acc[nt][0])) |
                                    ((unsigned int)__half_as_ushort(__float2half(acc[nt][1])) << 16);
            const unsigned int hi = (unsigned int)__half_as_ushort(__float2half(acc[nt][2])) |
                                    ((unsigned int)__half_as_ushort(__float2half(acc[nt][3])) << 16);
            u32x2 pk = {lo, hi};
            *(u32x2*)(gbuf + coll * 40 + fh * 8) = pk;
        }

        float gv[4][4];
        const int colbase = w * 64 + 4 * li;
        #pragma unroll
        for (int g = 0; g < 4; g++) {
            const u32x2 a = *(const u32x2*)(gbuf + (colbase + g) * 40 + ls * 8);
            gv[g][0] = __half2float(__ushort_as_half((unsigned short)(a[0] & 0xffff)));
            gv[g][1] = __half2float(__ushort_as_half((unsigned short)(a[0] >> 16)));
            gv[g][2] = __half2float(__ushort_as_half((unsigned short)(a[1] & 0xffff)));
            gv[g][3] = __half2float(__ushort_as_half((unsigned short)(a[1] >> 16)));
        }
        unsigned long long hpack = 0ull;
        #pragma unroll
        for (int p2 = 0; p2 < 4; p2++) {
            const float ig = 1.f / (1.f + __expf(-gv[0][p2]));
            const float fg = 1.f / (1.f + __expf(-gv[1][p2]));
            const float e2 = __expf(2.f * gv[2][p2]);
            const float gg = 1.f - 2.f / (e2 + 1.f);
            const float og = 1.f / (1.f + __expf(-gv[3][p2]));
            const float c = fg * c_reg[p2] + ig * gg;
            c_reg[p2] = c;
            const float e2c = __expf(2.f * c);
            const float hv = og * (1.f - 2.f / (e2c + 1.f));
            const unsigned short hb = f2bf(hv);
            const int s = ls * 4 + p2;
            *(unsigned short*)(hbuf + ((s * 512 + kglob * 2) ^ ((s & 7) << 4))) = hb;
            hpack |= ((unsigned long long)hb) << (16 * p2);
        }

        if (t < 15)
            __hip_atomic_store(hx_me + ((t & 1) * 512 + khalf * 4 + ls), hpack, __ATOMIC_RELAXED, AGENT);
        #pragma unroll
        for (int nt = 0; nt < 4; nt++) { xh[nt][0] = xhn[nt][0]; xh[nt][1] = xhn[nt][1]; }
        tt = tn;
        __syncthreads();   // F
        if (t < 15 && tid == 0)
            atomicExch(flg_me, base + (unsigned int)(t + 1));
    }
    {
        const int s = tid >> 5, q = tid & 31;
        const int ba = (s * 512 + (kh * 128 + q * 4) * 2) ^ ((s & 7) << 4);
        const u32x2 hv = *(const u32x2*)(hbuf + ba);
        const size_t row = out_mode ? ((size_t)(seq0 + s) * 16 + tt)
                                    : ((size_t)st * 256 + (size_t)tt * 16 + s);
        *(u32x2*)(out + row * 512 + dir * 256 + kh * 128 + q * 4) = hv;
    }
}

// ---------------- final conv3d 1x1x1: reads CONV f16 directly via index map ----------------
__global__ __launch_bounds__(256) void k_conv3f(const __half* __restrict__ CONV,
        const float* __restrict__ w, const float* __restrict__ bias, float* __restrict__ out) {
    __shared__ float xl[64 * 32];
    __shared__ float wl[64 * 64];
    const int bb = blockIdx.y;
    const int p0 = blockIdx.x * 32;
    const int tid = threadIdx.x;
    for (int i = tid; i < 64 * 32; i += 256) {
        const int c = i & 63, pp = i >> 6;
        const int p = p0 + pp;
        const int n_ = bb * 16 + (p & 15), b_ = (p >> 4) & 15, a_ = (p >> 8) & 15;
        const int r = (n_ * 16 + b_) * 16 + a_;
        xl[c * 32 + pp] = __half2float(CONV[(size_t)r * 64 + c]);
    }
    for (int i = tid; i < 64 * 64; i += 256) wl[i] = w[i];
    __syncthreads();
    const int pp = tid & 31, og = tid >> 5;
    #pragma unroll
    for (int oj = 0; oj < 8; oj++) {
        const int o = og * 8 + oj;
        float acc = bias[o];
        #pragma unroll 16
        for (int c = 0; c < 64; c++) acc += xl[c * 32 + pp] * wl[o * 64 + c];
        out[((size_t)bb * 64 + o) * 4096 + p0 + pp] = acc;
    }
}

extern "C" void kernel_launch(void* const* d_in, const int* in_sizes, int n_in,
                              void* d_out, int out_size, void* d_ws, size_t ws_size,
                              hipStream_t stream) {
    (void)in_sizes; (void)n_in; (void)out_size; (void)ws_size;
    const float* x     = (const float*)d_in[0];
    const float* vwihf = (const float*)d_in[1];
    const float* vwhhf = (const float*)d_in[2];
    const float* vbf   = (const float*)d_in[3];
    const float* vwihb = (const float*)d_in[4];
    const float* vwhhb = (const float*)d_in[5];
    const float* vbb   = (const float*)d_in[6];
    const float* hwihf = (const float*)d_in[7];
    const float* hwhhf = (const float*)d_in[8];
    const float* hbf   = (const float*)d_in[9];
    const float* hwihb = (const float*)d_in[10];
    const float* hwhhb = (const float*)d_in[11];
    const float* hbb   = (const float*)d_in[12];
    const float* c2w   = (const float*)d_in[13];
    const float* c2b   = (const float*)d_in[14];
    const float* c3w   = (const float*)d_in[15];
    const float* c3b   = (const float*)d_in[16];

    char* p = (char*)d_ws;
    auto alloc = [&](size_t bytes) { char* r = p; p += (bytes + 255) & ~((size_t)255); return r; };
    unsigned short* bVWIHf = (unsigned short*)alloc((size_t)1024 * 64 * 2);
    unsigned short* bVWIHb = (unsigned short*)alloc((size_t)1024 * 64 * 2);
    unsigned short* bVWHHf = (unsigned short*)alloc((size_t)1024 * 256 * 2);
    unsigned short* bVWHHb = (unsigned short*)alloc((size_t)1024 * 256 * 2);
    unsigned short* bHWIHf = (unsigned short*)alloc((size_t)1024 * 512 * 2);
    unsigned short* bHWIHb = (unsigned short*)alloc((size_t)1024 * 512 * 2);
    unsigned short* bHWHHf = (unsigned short*)alloc((size_t)1024 * 256 * 2);
    unsigned short* bHWHHb = (unsigned short*)alloc((size_t)1024 * 256 * 2);
    unsigned short* bC2W   = (unsigned short*)alloc((size_t)128 * 512 * 2);
    float* pVBf = (float*)alloc(1024 * 4);
    float* pVBb = (float*)alloc(1024 * 4);
    float* pHBf = (float*)alloc(1024 * 4);
    float* pHBb = (float*)alloc(1024 * 4);
    unsigned long long* HX = (unsigned long long*)alloc((size_t)128 * 8192);
    unsigned int* FLG = (unsigned int*)alloc((size_t)128 * 256);
    float* XA = (float*)alloc((size_t)524288 * 4);
    float* XB = (float*)alloc((size_t)524288 * 4);
    unsigned short* VIN = (unsigned short*)alloc((size_t)8192 * 64 * 2);
    __half* XW = (__half*)alloc((size_t)2 * 8192 * 1024 * 2);
    unsigned short* S_   = (unsigned short*)alloc((size_t)8192 * 512 * 2);
    unsigned short* HOUT = (unsigned short*)alloc((size_t)8192 * 512 * 2);
    __half* CONV = (__half*)VIN;   // reuse (VIN dead by conv time)

    hipMemsetAsync(bC2W, 0, (size_t)128 * 512 * 2, stream);
    hipMemsetAsync(FLG, 0, (size_t)128 * 256, stream);
    CastW cw;
    const float* srcs[9] = {vwihf, vwihb, vwhhf, vwhhb, hwihf, hwihb, hwhhf, hwhhb, c2w};
    unsigned short* dsts[9] = {bVWIHf, bVWIHb, bVWHHf, bVWHHb, bHWIHf, bHWIHb, bHWHHf, bHWHHb, bC2W};
    const int ns[9] = {65536, 65536, 262144, 262144, 524288, 524288, 262144, 262144, 32768};
    const int Ls[9] = {6, 6, 8, 8, 9, 9, 8, 8, 9};
    const int pm[9] = {1, 1, 1, 1, 1, 1, 1, 1, 0};
    for (int i = 0; i < 9; i++) { cw.src[i] = srcs[i]; cw.dst[i] = dsts[i]; cw.n[i] = ns[i]; cw.L[i] = Ls[i]; cw.perm[i] = pm[i]; }
    k_castw<<<dim3(2048, 9), 256, 0, stream>>>(cw);
    CastB cb;
    cb.src[0] = vbf; cb.dst[0] = pVBf;
    cb.src[1] = vbb; cb.dst[1] = pVBb;
    cb.src[2] = hbf; cb.dst[2] = pHBf;
    cb.src[3] = hbb; cb.dst[3] = pHBb;
    k_castb<<<dim3(4, 4), 256, 0, stream>>>(cb);

    const int SMs[3] = {256, 16, 1}, SAs[3] = {16, 256, 256}, SBs[3] = {1, 1, 16};
    for (int s = 0; s < 3; s++) {
        const float* Xin = (s == 0) ? x : ((s == 1) ? XA : XB);
        float* Xout = (s == 0) ? XA : XB;
        k_gather<<<512, 256, 0, stream>>>(Xin, VIN, SMs[s], SAs[s], SBs[s]);
        k_gemm<<<dim3(64, 8, 2), 256, 0, stream>>>(VIN, 64, bVWIHf, bVWIHb, pVBf, pVBb,
                                                   XW, 1024, 1024, 0, nullptr, 0, 0, 0);
        k_scan<<<dim3(32, 2, 2), 512, 0, stream>>>(XW, bVWHHf, bVWHHb, S_, 0, HX, FLG, s * 2 + 0);
        k_gemm<<<dim3(64, 8, 2), 256, 0, stream>>>(S_, 512, bHWIHf, bHWIHb, pHBf, pHBb,
                                                   XW, 1024, 1024, 0, nullptr, 0, 0, 0);
        k_scan<<<dim3(32, 2, 2), 512, 0, stream>>>(XW, bHWHHf, bHWHHb, HOUT, 1, HX, FLG, s * 2 + 1);
        if (s < 2)
            k_gemm<<<dim3(64, 1, 1), 256, 0, stream>>>(HOUT, 512, bC2W, bC2W, c2b, c2b,
                                                       CONV, 64, 64, 1, Xout, SMs[s], SAs[s], SBs[s]);
        else
            k_gemm<<<dim3(64, 1, 1), 256, 0, stream>>>(HOUT, 512, bC2W, bC2W, c2b, c2b,
                                                       CONV, 64, 64, 0, nullptr, 0, 0, 0);
    }
    k_conv3f<<<dim3(128, 2), 256, 0, stream>>>(CONV, c3w, c3b, (float*)d_out);
}

// Round 13
// 585.327 us; speedup vs baseline: 1.3652x; 1.0005x over previous
//
#include <hip/hip_runtime.h>
#include <hip/hip_bf16.h>
#include <hip/hip_fp16.h>

// Renet3d. Matmuls: bf16 MFMA 16x16x32, fp32 accum.
// v13 = v12 + k_scan LDS padding to force 1 block/CU (pair-blocks were plausibly
// sharing CUs at 2 blocks/CU, serializing the per-step chain on shared SIMDs).
// Scan logic byte-identical to v10/v12 (proven 59.9us structure).

typedef __attribute__((ext_vector_type(8))) short bf16x8;
typedef __attribute__((ext_vector_type(4))) float f32x4;
typedef __attribute__((ext_vector_type(4))) unsigned int u32x4;
typedef __attribute__((ext_vector_type(2))) unsigned int u32x2;

#define AGENT __HIP_MEMORY_SCOPE_AGENT

__device__ __forceinline__ unsigned short f2bf(float f) {
    unsigned int u = __float_as_uint(f);
    u += 0x7fffu + ((u >> 16) & 1u);
    return (unsigned short)(u >> 16);
}
__device__ __forceinline__ void gload16(const void* g, void* l) {
    __builtin_amdgcn_global_load_lds((const __attribute__((address_space(1))) unsigned int*)g,
                                     (__attribute__((address_space(3))) unsigned int*)l, 16, 0, 0);
}

// ---------------- weight casts ----------------
struct CastW { const float* src[9]; unsigned short* dst[9]; int n[9]; int L[9]; int perm[9]; };
__global__ void k_castw(CastW j) {
    const int a = blockIdx.y;
    const int i = blockIdx.x * 256 + threadIdx.x;
    if (i >= j.n[a]) return;
    const int L = j.L[a];
    const int r = i >> L, c = i & ((1 << L) - 1);
    const int dr = j.perm[a] ? ((r & 255) * 4 + (r >> 8)) : r;
    j.dst[a][(dr << L) | c] = f2bf(j.src[a][i]);
}
struct CastB { const float* src[4]; float* dst[4]; };
__global__ void k_castb(CastB j) {
    const int a = blockIdx.y;
    const int i = blockIdx.x * 256 + threadIdx.x;
    j.dst[a][(i & 255) * 4 + (i >> 8)] = j.src[a][i];
}

// ---------------- gather: 5D f32 -> v_in bf16 [512*16][64], coalesced reads ----------------
__global__ void k_gather(const float* __restrict__ X, unsigned short* __restrict__ vin,
                         int sm, int sa, int sb) {
    __shared__ unsigned short sd[16 * 68];
    const int seq = blockIdx.x;
    const int n = seq >> 4, a = seq & 15;
    const size_t base = (size_t)(n >> 4) * 64 * 4096 + (size_t)sm * (n & 15) + (size_t)sa * a;
    const int t = threadIdx.x;
    #pragma unroll
    for (int j = 0; j < 4; j++) {
        const int i = t + j * 256;
        const int c = i >> 4, b = i & 15;
        sd[b * 68 + c] = f2bf(X[base + (size_t)c * 4096 + (size_t)sb * b]);
    }
    __syncthreads();
    const int r = t >> 4, c0 = (t & 15) * 4;
    unsigned long long v;
    unsigned short* sp = &sd[r * 68 + c0];
    v = (unsigned long long)sp[0] | ((unsigned long long)sp[1] << 16) |
        ((unsigned long long)sp[2] << 32) | ((unsigned long long)sp[3] << 48);
    *(unsigned long long*)(vin + (size_t)seq * 1024 + r * 64 + c0) = v;
}

// ---------------- GEMM: z-batched, global_load_lds staging, optional fused 5D scatter ----------------
__global__ __launch_bounds__(256) void k_gemm(const unsigned short* __restrict__ A, int K,
        const unsigned short* __restrict__ W0, const unsigned short* __restrict__ W1,
        const float* __restrict__ bias0, const float* __restrict__ bias1,
        __half* __restrict__ C, int ldc, int nvalid,
        int mode, float* __restrict__ out5d, int sm, int sa, int sb) {
    __shared__ unsigned short Alds[128 * 32];
    __shared__ unsigned short Blds[128 * 32];
    const unsigned short* W = blockIdx.z ? W1 : W0;
    const float* bias = blockIdx.z ? bias1 : bias0;
    C += (size_t)blockIdx.z * 8192 * ldc;
    const int m0 = blockIdx.x * 128, n0 = blockIdx.y * 128;
    const int tid = threadIdx.x;
    const int lane = tid & 63, wid = tid >> 6;
    const int wr = wid >> 1, wc = wid & 1;
    const int fl = lane & 15, fh = lane >> 4;
    f32x4 acc[4][4];
    #pragma unroll
    for (int mi = 0; mi < 4; mi++)
        #pragma unroll
        for (int ni = 0; ni < 4; ni++) { f32x4 z = {0.f,0.f,0.f,0.f}; acc[mi][ni] = z; }

    const int srow = wid * 32 + (lane >> 2);
    const int swz = ((lane & 3) ^ ((lane >> 2) & 3)) * 8;

    for (int k0 = 0; k0 < K; k0 += 32) {
        __syncthreads();
        gload16(A + (size_t)(m0 + srow) * K + k0 + swz,      &Alds[(wid * 32) * 32]);
        gload16(A + (size_t)(m0 + srow + 16) * K + k0 + swz, &Alds[(wid * 32 + 16) * 32]);
        gload16(W + (size_t)(n0 + srow) * K + k0 + swz,      &Blds[(wid * 32) * 32]);
        gload16(W + (size_t)(n0 + srow + 16) * K + k0 + swz, &Blds[(wid * 32 + 16) * 32]);
        __syncthreads();
        bf16x8 af[4], bfb[4];
        const int rc = (fh ^ (fl & 3)) * 8;
        #pragma unroll
        for (int i = 0; i < 4; i++) {
            af[i]  = *(const bf16x8*)&Alds[(wr * 64 + i * 16 + fl) * 32 + rc];
            bfb[i] = *(const bf16x8*)&Blds[(wc * 64 + i * 16 + fl) * 32 + rc];
        }
        #pragma unroll
        for (int mi = 0; mi < 4; mi++)
            #pragma unroll
            for (int ni = 0; ni < 4; ni++)
                acc[mi][ni] = __builtin_amdgcn_mfma_f32_16x16x32_bf16(af[mi], bfb[ni], acc[mi][ni], 0, 0, 0);
    }
    const int rl = fh * 4;
    #pragma unroll
    for (int ni = 0; ni < 4; ni++) {
        const int col = n0 + wc * 64 + ni * 16 + fl;
        if (col < nvalid) {
            const float bs = bias[col];
            #pragma unroll
            for (int mi = 0; mi < 4; mi++) {
                const int row = m0 + wr * 64 + mi * 16 + rl;
                #pragma unroll
                for (int j = 0; j < 4; j++) {
                    const float v = acc[mi][ni][j] + bs;
                    if (mode) {
                        const int r = row + j;
                        const int n_ = r >> 8, b_ = (r >> 4) & 15, a_ = r & 15;
                        out5d[(size_t)(n_ >> 4) * 262144 + (size_t)sm * (n_ & 15) +
                              (size_t)sa * a_ + (size_t)sb * b_ + (size_t)col * 4096] = v;
                    } else {
                        C[(size_t)(row + j) * ldc + col] = __float2half(v);
                    }
                }
            }
        }
    }
}

// ---------------- LSTM scan (v10 logic + LDS pad -> 1 block/CU) ----------------
__global__ __launch_bounds__(512, 2) void k_scan(const __half* __restrict__ xw,
        const unsigned short* __restrict__ whh_f, const unsigned short* __restrict__ whh_b,
        unsigned short* __restrict__ out, int out_mode,
        unsigned long long* __restrict__ HX, unsigned int* __restrict__ FLG, int phase) {
    __shared__ __align__(16) char gbuf[512 * 40];
    __shared__ __align__(16) char hbuf[16 * 512];
    __shared__ char occ_pad[56 * 1024];   // force 1 block/CU (2x would exceed 160KB LDS)
    const int tid = threadIdx.x;
    if (out_mode == 2) ((volatile char*)occ_pad)[tid] = 0;   // never true; defeats DCE
    const int lane = tid & 63, w = tid >> 6;
    const int fl = lane & 15, fh = lane >> 4;
    const int st = blockIdx.x, dir = blockIdx.y, kh = blockIdx.z;
    const int seq0 = st * 16;
    const unsigned short* whh_k = (dir ? whh_b : whh_f) + (size_t)kh * 512 * 256;
    const __half* xwd = xw + (size_t)dir * (8192 * 1024);
    const int C0g = kh * 512 + w * 64;
    const int slot = ((dir * 32 + st) * 2 + kh);
    unsigned long long* hx_me = HX + (size_t)slot * 1024;
    const unsigned long long* hx_p = HX + (size_t)(slot ^ 1) * 1024;
    unsigned int* flg_me = FLG + slot * 64;
    unsigned int* flg_p  = FLG + (slot ^ 1) * 64;
    const unsigned int base = 16u * (unsigned int)phase;
    const int kOwnB = kh * 4;
    const int kParB = (1 - kh) * 4;

    #pragma unroll
    for (int i = 0; i < 4; i++) ((unsigned int*)hbuf)[tid + i * 512] = 0u;

    bf16x8 wown[4][4], wpar[4][4];
    #pragma unroll
    for (int nt = 0; nt < 4; nt++) {
        const unsigned short* rowp = whh_k + (size_t)(w * 64 + nt * 16 + fl) * 256 + fh * 8;
        #pragma unroll
        for (int i = 0; i < 4; i++) {
            wown[nt][i] = *(const bf16x8*)(rowp + (kOwnB + i) * 32);
            wpar[nt][i] = *(const bf16x8*)(rowp + (kParB + i) * 32);
        }
    }

    const int li = lane & 15, ls = lane >> 4;
    const int khalf = w * 16 + li;
    const int kglob = kh * 128 + khalf;
    float c_reg[4] = {0.f, 0.f, 0.f, 0.f};

    int tt = dir ? 15 : 0;
    const int tstep = dir ? -1 : 1;

    unsigned int xh[4][2], xhn[4][2];
    #pragma unroll
    for (int nt = 0; nt < 4; nt++)
        #pragma unroll
        for (int j2 = 0; j2 < 2; j2++) {
            const size_t b_ = ((size_t)(seq0 + fh * 4 + j2 * 2) * 16 + tt) * 1024 + C0g + nt * 16 + fl;
            const unsigned short h0 = __half_as_ushort(xwd[b_]);
            const unsigned short h1 = __half_as_ushort(xwd[b_ + 16 * 1024]);
            xh[nt][j2] = (unsigned int)h0 | ((unsigned int)h1 << 16);
        }

    __syncthreads();

    for (int t = 0; t < 16; t++) {
        if (t > 0) {
            const int ttp = tt - tstep;
            const int s = tid >> 5, q = tid & 31;
            const int ba = (s * 512 + (kh * 128 + q * 4) * 2) ^ ((s & 7) << 4);
            const u32x2 hv = *(const u32x2*)(hbuf + ba);
            const size_t row = out_mode ? ((size_t)(seq0 + s) * 16 + ttp)
                                        : ((size_t)st * 256 + (size_t)ttp * 16 + s);
            *(u32x2*)(out + row * 512 + dir * 256 + kh * 128 + q * 4) = hv;
        }
        bf16x8 afr[4];
        #pragma unroll
        for (int i = 0; i < 4; i++) {
            const int ba = (fl * 512 + (kOwnB + i) * 64 + fh * 16) ^ ((fl & 7) << 4);
            afr[i] = *(const bf16x8*)(hbuf + ba);
        }
        f32x4 acc[4];
        #pragma unroll
        for (int nt = 0; nt < 4; nt++) {
            acc[nt][0] = __half2float(__ushort_as_half((unsigned short)(xh[nt][0] & 0xffff)));
            acc[nt][1] = __half2float(__ushort_as_half((unsigned short)(xh[nt][0] >> 16)));
            acc[nt][2] = __half2float(__ushort_as_half((unsigned short)(xh[nt][1] & 0xffff)));
            acc[nt][3] = __half2float(__ushort_as_half((unsigned short)(xh[nt][1] >> 16)));
            #pragma unroll
            for (int i = 0; i < 4; i++)
                acc[nt] = __builtin_amdgcn_mfma_f32_16x16x32_bf16(afr[i], wown[nt][i], acc[nt], 0, 0, 0);
        }
        if (t > 0) {
            if (tid == 0) {
                const unsigned int want = base + (unsigned int)t;
                while (atomicAdd(flg_p, 0u) < want) __builtin_amdgcn_s_sleep(1);
            }
            asm volatile("s_barrier" ::: "memory");   // E1
            const unsigned long long pv =
                __hip_atomic_load(hx_p + (((t - 1) & 1) * 512 + tid), __ATOMIC_RELAXED, AGENT);
            const int kl = tid >> 2, sl0 = (tid & 3) * 4;
            const int kp = (1 - kh) * 128 + kl;
            #pragma unroll
            for (int e = 0; e < 4; e++) {
                const int s = sl0 + e;
                *(unsigned short*)(hbuf + ((s * 512 + kp * 2) ^ ((s & 7) << 4))) =
                    (unsigned short)(pv >> (16 * e));
            }
        }
        asm volatile("s_waitcnt lgkmcnt(0)\n\ts_barrier" ::: "memory");   // E2

        const int tn = (t < 15) ? tt + tstep : tt;
        #pragma unroll
        for (int nt = 0; nt < 4; nt++)
            #pragma unroll
            for (int j2 = 0; j2 < 2; j2++) {
                const size_t b_ = ((size_t)(seq0 + fh * 4 + j2 * 2) * 16 + tn) * 1024 + C0g + nt * 16 + fl;
                const unsigned short h0 = __half_as_ushort(xwd[b_]);
                const unsigned short h1 = __half_as_ushort(xwd[b_ + 16 * 1024]);
                xhn[nt][j2] = (unsigned int)h0 | ((unsigned int)h1 << 16);
            }

        #pragma unroll
        for (int i = 0; i < 4; i++) {
            const int ba = (fl * 512 + (kParB + i) * 64 + fh * 16) ^ ((fl & 7) << 4);
            afr[i] = *(const bf16x8*)(hbuf + ba);
        }
        #pragma unroll
        for (int nt = 0; nt < 4; nt++) {
            #pragma unroll
            for (int i = 0; i < 4; i++)
                acc[nt] = __builtin_amdgcn_mfma_f32_16x16x32_bf16(afr[i], wpar[nt][i], acc[nt], 0, 0, 0);
            const int coll = w * 64 + nt * 16 + fl;
            const unsigned int lo = (unsigned int)__half_as_ushort(__float2half(acc[nt][0])) |
                                    ((unsigned int)__half_as_ushort(__float2half(acc[nt][1])) << 16);
            const unsigned int hi = (unsigned int)__half_as_ushort(__float2half(acc[nt][2])) |
                                    ((unsigned int)__half_as_ushort(__float2half(acc[nt][3])) << 16);
            u32x2 pk = {lo, hi};
            *(u32x2*)(gbuf + coll * 40 + fh * 8) = pk;
        }

        float gv[4][4];
        const int colbase = w * 64 + 4 * li;
        #pragma unroll
        for (int g = 0; g < 4; g++) {
            const u32x2 a = *(const u32x2*)(gbuf + (colbase + g) * 40 + ls * 8);
            gv[g][0] = __half2float(__ushort_as_half((unsigned short)(a[0] & 0xffff)));
            gv[g][1] = __half2float(__ushort_as_half((unsigned short)(a[0] >> 16)));
            gv[g][2] = __half2float(__ushort_as_half((unsigned short)(a[1] & 0xffff)));
            gv[g][3] = __half2float(__ushort_as_half((unsigned short)(a[1] >> 16)));
        }
        unsigned long long hpack = 0ull;
        #pragma unroll
        for (int p2 = 0; p2 < 4; p2++) {
            const float ig = 1.f / (1.f + __expf(-gv[0][p2]));
            const float fg = 1.f / (1.f + __expf(-gv[1][p2]));
            const float e2 = __expf(2.f * gv[2][p2]);
            const float gg = 1.f - 2.f / (e2 + 1.f);
            const float og = 1.f / (1.f + __expf(-gv[3][p2]));
            const float c = fg * c_reg[p2] + ig * gg;
            c_reg[p2] = c;
            const float e2c = __expf(2.f * c);
            const float hv = og * (1.f - 2.f / (e2c + 1.f));
            const unsigned short hb = f2bf(hv);
            const int s = ls * 4 + p2;
            *(unsigned short*)(hbuf + ((s * 512 + kglob * 2) ^ ((s & 7) << 4))) = hb;
            hpack |= ((unsigned long long)hb) << (16 * p2);
        }

        if (t < 15)
            __hip_atomic_store(hx_me + ((t & 1) * 512 + khalf * 4 + ls), hpack, __ATOMIC_RELAXED, AGENT);
        #pragma unroll
        for (int nt = 0; nt < 4; nt++) { xh[nt][0] = xhn[nt][0]; xh[nt][1] = xhn[nt][1]; }
        tt = tn;
        __syncthreads();   // F
        if (t < 15 && tid == 0)
            atomicExch(flg_me, base + (unsigned int)(t + 1));
    }
    {
        const int s = tid >> 5, q = tid & 31;
        const int ba = (s * 512 + (kh * 128 + q * 4) * 2) ^ ((s & 7) << 4);
        const u32x2 hv = *(const u32x2*)(hbuf + ba);
        const size_t row = out_mode ? ((size_t)(seq0 + s) * 16 + tt)
                                    : ((size_t)st * 256 + (size_t)tt * 16 + s);
        *(u32x2*)(out + row * 512 + dir * 256 + kh * 128 + q * 4) = hv;
    }
}

// ---------------- final conv3d 1x1x1 ----------------
__global__ __launch_bounds__(256) void k_conv3f(const __half* __restrict__ CONV,
        const float* __restrict__ w, const float* __restrict__ bias, float* __restrict__ out) {
    __shared__ float xl[64 * 32];
    __shared__ float wl[64 * 64];
    const int bb = blockIdx.y;
    const int p0 = blockIdx.x * 32;
    const int tid = threadIdx.x;
    for (int i = tid; i < 64 * 32; i += 256) {
        const int c = i & 63, pp = i >> 6;
        const int p = p0 + pp;
        const int n_ = bb * 16 + (p & 15), b_ = (p >> 4) & 15, a_ = (p >> 8) & 15;
        const int r = (n_ * 16 + b_) * 16 + a_;
        xl[c * 32 + pp] = __half2float(CONV[(size_t)r * 64 + c]);
    }
    for (int i = tid; i < 64 * 64; i += 256) wl[i] = w[i];
    __syncthreads();
    const int pp = tid & 31, og = tid >> 5;
    #pragma unroll
    for (int oj = 0; oj < 8; oj++) {
        const int o = og * 8 + oj;
        float acc = bias[o];
        #pragma unroll 16
        for (int c = 0; c < 64; c++) acc += xl[c * 32 + pp] * wl[o * 64 + c];
        out[((size_t)bb * 64 + o) * 4096 + p0 + pp] = acc;
    }
}

extern "C" void kernel_launch(void* const* d_in, const int* in_sizes, int n_in,
                              void* d_out, int out_size, void* d_ws, size_t ws_size,
                              hipStream_t stream) {
    (void)in_sizes; (void)n_in; (void)out_size; (void)ws_size;
    const float* x     = (const float*)d_in[0];
    const float* vwihf = (const float*)d_in[1];
    const float* vwhhf = (const float*)d_in[2];
    const float* vbf   = (const float*)d_in[3];
    const float* vwihb = (const float*)d_in[4];
    const float* vwhhb = (const float*)d_in[5];
    const float* vbb   = (const float*)d_in[6];
    const float* hwihf = (const float*)d_in[7];
    const float* hwhhf = (const float*)d_in[8];
    const float* hbf   = (const float*)d_in[9];
    const float* hwihb = (const float*)d_in[10];
    const float* hwhhb = (const float*)d_in[11];
    const float* hbb   = (const float*)d_in[12];
    const float* c2w   = (const float*)d_in[13];
    const float* c2b   = (const float*)d_in[14];
    const float* c3w   = (const float*)d_in[15];
    const float* c3b   = (const float*)d_in[16];

    char* p = (char*)d_ws;
    auto alloc = [&](size_t bytes) { char* r = p; p += (bytes + 255) & ~((size_t)255); return r; };
    unsigned short* bVWIHf = (unsigned short*)alloc((size_t)1024 * 64 * 2);
    unsigned short* bVWIHb = (unsigned short*)alloc((size_t)1024 * 64 * 2);
    unsigned short* bVWHHf = (unsigned short*)alloc((size_t)1024 * 256 * 2);
    unsigned short* bVWHHb = (unsigned short*)alloc((size_t)1024 * 256 * 2);
    unsigned short* bHWIHf = (unsigned short*)alloc((size_t)1024 * 512 * 2);
    unsigned short* bHWIHb = (unsigned short*)alloc((size_t)1024 * 512 * 2);
    unsigned short* bHWHHf = (unsigned short*)alloc((size_t)1024 * 256 * 2);
    unsigned short* bHWHHb = (unsigned short*)alloc((size_t)1024 * 256 * 2);
    unsigned short* bC2W   = (unsigned short*)alloc((size_t)128 * 512 * 2);
    float* pVBf = (float*)alloc(1024 * 4);
    float* pVBb = (float*)alloc(1024 * 4);
    float* pHBf = (float*)alloc(1024 * 4);
    float* pHBb = (float*)alloc(1024 * 4);
    unsigned long long* HX = (unsigned long long*)alloc((size_t)128 * 8192);
    unsigned int* FLG = (unsigned int*)alloc((size_t)128 * 256);
    float* XA = (float*)alloc((size_t)524288 * 4);
    float* XB = (float*)alloc((size_t)524288 * 4);
    unsigned short* VIN = (unsigned short*)alloc((size_t)8192 * 64 * 2);
    __half* XW = (__half*)alloc((size_t)2 * 8192 * 1024 * 2);
    unsigned short* S_   = (unsigned short*)alloc((size_t)8192 * 512 * 2);
    unsigned short* HOUT = (unsigned short*)alloc((size_t)8192 * 512 * 2);
    __half* CONV = (__half*)VIN;

    hipMemsetAsync(bC2W, 0, (size_t)128 * 512 * 2, stream);
    hipMemsetAsync(FLG, 0, (size_t)128 * 256, stream);
    CastW cw;
    const float* srcs[9] = {vwihf, vwihb, vwhhf, vwhhb, hwihf, hwihb, hwhhf, hwhhb, c2w};
    unsigned short* dsts[9] = {bVWIHf, bVWIHb, bVWHHf, bVWHHb, bHWIHf, bHWIHb, bHWHHf, bHWHHb, bC2W};
    const int ns[9] = {65536, 65536, 262144, 262144, 524288, 524288, 262144, 262144, 32768};
    const int Ls[9] = {6, 6, 8, 8, 9, 9, 8, 8, 9};
    const int pm[9] = {1, 1, 1, 1, 1, 1, 1, 1, 0};
    for (int i = 0; i < 9; i++) { cw.src[i] = srcs[i]; cw.dst[i] = dsts[i]; cw.n[i] = ns[i]; cw.L[i] = Ls[i]; cw.perm[i] = pm[i]; }
    k_castw<<<dim3(2048, 9), 256, 0, stream>>>(cw);
    CastB cb;
    cb.src[0] = vbf; cb.dst[0] = pVBf;
    cb.src[1] = vbb; cb.dst[1] = pVBb;
    cb.src[2] = hbf; cb.dst[2] = pHBf;
    cb.src[3] = hbb; cb.dst[3] = pHBb;
    k_castb<<<dim3(4, 4), 256, 0, stream>>>(cb);

    const int SMs[3] = {256, 16, 1}, SAs[3] = {16, 256, 256}, SBs[3] = {1, 1, 16};
    for (int s = 0; s < 3; s++) {
        const float* Xin = (s == 0) ? x : ((s == 1) ? XA : XB);
        float* Xout = (s == 0) ? XA : XB;
        k_gather<<<512, 256, 0, stream>>>(Xin, VIN, SMs[s], SAs[s], SBs[s]);
        k_gemm<<<dim3(64, 8, 2), 256, 0, stream>>>(VIN, 64, bVWIHf, bVWIHb, pVBf, pVBb,
                                                   XW, 1024, 1024, 0, nullptr, 0, 0, 0);
        k_scan<<<dim3(32, 2, 2), 512, 0, stream>>>(XW, bVWHHf, bVWHHb, S_, 0, HX, FLG, s * 2 + 0);
        k_gemm<<<dim3(64, 8, 2), 256, 0, stream>>>(S_, 512, bHWIHf, bHWIHb, pHBf, pHBb,
                                                   XW, 1024, 1024, 0, nullptr, 0, 0, 0);
        k_scan<<<dim3(32, 2, 2), 512, 0, stream>>>(XW, bHWHHf, bHWHHb, HOUT, 1, HX, FLG, s * 2 + 1);
        if (s < 2)
            k_gemm<<<dim3(64, 1, 1), 256, 0, stream>>>(HOUT, 512, bC2W, bC2W, c2b, c2b,
                                                       CONV, 64, 64, 1, Xout, SMs[s], SAs[s], SBs[s]);
        else
            k_gemm<<<dim3(64, 1, 1), 256, 0, stream>>>(HOUT, 512, bC2W, bC2W, c2b, c2b,
                                                       CONV, 64, 64, 0, nullptr, 0, 0, 0);
    }
    k_conv3f<<<dim3(128, 2), 256, 0, stream>>>(CONV, c3w, c3b, (float*)d_out);
}